// Round 11
// baseline (253.651 us; speedup 1.0000x reference)
//
#include <hip/hip_runtime.h>
#include <hip/hip_bf16.h>
#include <stdint.h>
#include <math.h>

// Problem constants
#define NB      16
#define LL      1024
#define EE      512
#define NHEADS  8
#define DFF     2048
#define NLEVELS 10
#define NSCALES 11
#define BROWS   (NB * LL)       // 16384

typedef unsigned short u16;
typedef __attribute__((ext_vector_type(8))) short bf16x8;   // 8 bf16 = 4 VGPRs (MFMA A/B frag)
typedef __attribute__((ext_vector_type(4))) float f32x4;    // MFMA C/D frag

// ---------------- workspace layout (byte offsets) ----------------
static const size_t B_SRCBF = 0;                         // 16,777,216
static const size_t B_LVLBF = 16777216;                  // 16,760,832
static const size_t B_QKV   = 33538048;                  // 50,331,648
static const size_t B_KVS   = 83869696;                  // 33,521,664
static const size_t B_OBF   = 117391360;                 // 16,777,216
static const size_t B_X     = 134168576;                 // 33,554,432
static const size_t B_XBF   = 167723008;                 // 16,777,216
static const size_t B_WBF   = 184500224;                 // weights
static const size_t B_FFH   = 0;                         // overlaps dead-by-then buffers

// ---------------- helpers ----------------
__device__ __forceinline__ u16 f2bf(float x) {
    union { float f; uint32_t u; } c; c.f = x;
    uint32_t u = c.u + 0x7FFFu + ((c.u >> 16) & 1u);
    return (u16)(u >> 16);
}
__device__ __forceinline__ float bf2f(u16 v) {
    union { uint32_t u; float f; } c; c.u = ((uint32_t)v) << 16; return c.f;
}
__device__ __forceinline__ void ld8bf(const u16* p, float* f) {
    uint4 r = *(const uint4*)p;
    uint32_t ws[4] = { r.x, r.y, r.z, r.w };
    #pragma unroll
    for (int j = 0; j < 4; j++) {
        union { uint32_t u; float g; } lo, hi;
        lo.u = ws[j] << 16; hi.u = ws[j] & 0xFFFF0000u;
        f[2 * j] = lo.g; f[2 * j + 1] = hi.g;
    }
}
__device__ __forceinline__ void gload16(const u16* g, u16* l) {
    __builtin_amdgcn_global_load_lds(
        (const __attribute__((address_space(1))) void*)g,
        (__attribute__((address_space(3))) void*)l, 16, 0, 0);
}

// ---------------------------------------------------------------------------
// Fused cast kernel: src + 4 weight tensors -> bf16, plus conv_w repack.
// ---------------------------------------------------------------------------
__global__ void cast_all_kernel(const float* __restrict__ s0, const float* __restrict__ s1,
                                const float* __restrict__ s2, const float* __restrict__ s3,
                                const float* __restrict__ s4, const float* __restrict__ cw,
                                u16* __restrict__ d0, u16* __restrict__ d1,
                                u16* __restrict__ d2, u16* __restrict__ d3,
                                u16* __restrict__ d4, u16* __restrict__ dw)
{
    int bid = blockIdx.x;
    if (bid >= 11264) {   // conv_w repack: 81920 outputs
        int base = (bid - 11264) * 1024 + threadIdx.x * 4;
        #pragma unroll
        for (int j = 0; j < 4; j++) {
            int idx = base + j;
            int lvl = idx >> 13, rem = idx & 8191;
            int o = rem >> 7, ck = rem & 127;
            int k = ck >> 6, ci = ck & 63;
            dw[idx] = f2bf(cw[(lvl << 13) + (o << 7) + (ci << 1) + k]);
        }
        return;
    }
    const float* s; u16* d; int nt;
    if      (bid < 8192)  { s = s0; d = d0; nt = 2097152; }
    else if (bid < 8960)  { bid -= 8192;  s = s1; d = d1; nt = 196608; }
    else if (bid < 9216)  { bid -= 8960;  s = s2; d = d2; nt = 65536;  }
    else if (bid < 10240) { bid -= 9216;  s = s3; d = d3; nt = 262144; }
    else                  { bid -= 10240; s = s4; d = d4; nt = 262144; }
    int i = bid * 256 + threadIdx.x;
    if (i < nt) {
        float4 v = ((const float4*)s)[i];
        uint2 o;
        o.x = (uint32_t)f2bf(v.x) | ((uint32_t)f2bf(v.y) << 16);
        o.y = (uint32_t)f2bf(v.z) | ((uint32_t)f2bf(v.w) << 16);
        ((uint2*)d)[i] = o;
    }
}

// ---------------------------------------------------------------------------
// Conv chain kernel: levels 1..8 in ONE launch (unchanged).
// ---------------------------------------------------------------------------
__global__ __launch_bounds__(256, 2)
void conv_chain_kernel(const u16* __restrict__ src_bf, u16* __restrict__ lvl_bf,
                       const u16* __restrict__ cw, const float* __restrict__ cb)
{
    __shared__ u16 BIG[16384];   // 32KB
    __shared__ u16 MID[8192];    // 16KB
    __shared__ u16 WB[8192];     // 16KB: per-level weights [o][128]
    const int tid = threadIdx.x;
    const int l = tid & 63, w = tid >> 6;
    const int bid = blockIdx.x;          // n*32 + h*4 + q
    const int q  = bid & 3;
    const int h  = (bid >> 2) & 7;
    const int n  = bid >> 5;

    {
        const u16* base = src_bf + ((size_t)n * 1024 + q * 256) * 512 + h * 64;
        #pragma unroll
        for (int j = 0; j < 8; j++) {
            int c = j * 256 + w * 64 + l;
            int row = c >> 3, lch = c & 7;
            int gch = lch ^ (row & 7);
            gload16(base + (size_t)row * 512 + gch * 8,
                    BIG + (size_t)(j * 256 + w * 64) * 8);
        }
    }

    const u16* IN = BIG;
    u16* OUTb = MID;
    int R = 128;
    int T = 512;
    size_t rowOff = 0;
    for (int lvl = 1; lvl <= 8; lvl++) {
        {
            const u16* wsrc = cw + (size_t)(lvl - 1) * 8192;
            #pragma unroll
            for (int j = 0; j < 4; j++) {
                int c = j * 256 + w * 64 + l;
                int o = c >> 4, lch = c & 15;
                int gch = lch ^ (o & 7);
                gload16(wsrc + o * 128 + gch * 8, WB + (size_t)(j * 256 + w * 64) * 8);
            }
        }
        asm volatile("s_waitcnt vmcnt(0)" ::: "memory");
        __syncthreads();

        const int nrt = (R + 15) >> 4;
        const int maxil = 2 * R - 1;
        for (int f = w; f < nrt * 4; f += 4) {
            int rt = f >> 2, nc = f & 3;
            int o = nc * 16 + (l & 15);
            f32x4 acc = {0.f, 0.f, 0.f, 0.f};
            #pragma unroll
            for (int s = 0; s < 4; s++) {
                int il = 2 * (rt * 16 + (l & 15)) + (s >> 1);
                if (il > maxil) il = maxil;
                int ach = (((s & 1) * 4) + (l >> 4)) ^ (il & 7);
                bf16x8 av = *(const bf16x8*)(IN + il * 64 + ach * 8);
                int bch = (s * 4 + (l >> 4)) ^ (o & 7);
                bf16x8 bv = *(const bf16x8*)(WB + o * 128 + bch * 8);
                acc = __builtin_amdgcn_mfma_f32_16x16x32_bf16(av, bv, acc, 0, 0, 0);
            }
            float bb = cb[(lvl - 1) * 64 + o];
            #pragma unroll
            for (int reg = 0; reg < 4; reg++) {
                int rloc = rt * 16 + (l >> 4) * 4 + reg;
                if (rloc < R) {
                    float v = fmaxf(acc[reg] + bb, 0.f);
                    u16 b16 = f2bf(v);
                    lvl_bf[(rowOff + (size_t)n * T + (size_t)q * R + rloc) * 512 + h * 64 + o] = b16;
                    OUTb[rloc * 64 + (((o >> 3) ^ (rloc & 7)) << 3) + (o & 7)] = b16;
                }
            }
        }
        __syncthreads();
        const u16* tmp = IN; IN = OUTb; OUTb = (u16*)tmp;
        rowOff += (size_t)16 * T;
        T >>= 1; R >>= 1;
    }
}

// ---------------------------------------------------------------------------
// Conv tail: levels 9 and 10 (tiny). Block per (n,h).
// ---------------------------------------------------------------------------
__global__ void conv_tail_kernel(u16* __restrict__ lvl_bf, const u16* __restrict__ cw,
                                 const float* __restrict__ cb)
{
    const int h = blockIdx.x & 7, n = blockIdx.x >> 3;
    const int tid = threadIdx.x;
    __shared__ float L8s[4][64];
    __shared__ float L9s[2][64];
    {
        int r = tid >> 6, c = tid & 63;
        L8s[r][c] = bf2f(lvl_bf[((size_t)16256 + n * 4 + r) * 512 + h * 64 + c]);
    }
    __syncthreads();
    if (tid < 128) {
        int t = tid >> 6, o = tid & 63;
        const u16* wr = cw + (size_t)8 * 8192 + o * 128;
        float acc = cb[8 * 64 + o];
        #pragma unroll
        for (int k = 0; k < 2; k++)
            #pragma unroll 16
            for (int ci = 0; ci < 64; ci++)
                acc += L8s[2 * t + k][ci] * bf2f(wr[k * 64 + ci]);
        acc = fmaxf(acc, 0.f);
        L9s[t][o] = acc;
        lvl_bf[((size_t)16320 + n * 2 + t) * 512 + h * 64 + o] = f2bf(acc);
    }
    __syncthreads();
    if (tid < 64) {
        int o = tid;
        const u16* wr = cw + (size_t)9 * 8192 + o * 128;
        float acc = cb[9 * 64 + o];
        #pragma unroll
        for (int k = 0; k < 2; k++)
            #pragma unroll 16
            for (int ci = 0; ci < 64; ci++)
                acc += L9s[k][ci] * bf2f(wr[k * 64 + ci]);
        acc = fmaxf(acc, 0.f);
        lvl_bf[((size_t)16352 + n) * 512 + h * 64 + o] = f2bf(acc);
    }
}

// ---------------------------------------------------------------------------
// bf16 MFMA GEMM v5: 256x128 tile, BK=64, 8 waves (4M x 2N), per-wave 64x64.
// 8-phase-style schedule (2 phases per K-tile), per m201/T3+T4+T5:
//  phase0: 12 ds_reads (bv[4]x2ks + av rows 0-1) || stage-unit1(t+1)
//          -> lgkmcnt(0) -> setprio(1) 16 MFMA -> barrier
//  phase1: 4 ds_reads (av rows 2-3) -> lgkmcnt(0) -> 16 MFMA -> barrier
//  tile entry: stage-unit0(t+1); counted vmcnt(3) (never 0 mid-loop).
//  2-buffer LDS 96KB (1 block/CU; phase overlap replaces cross-block TLP).
//  Swizzle p = c ^ (row&7) (8 chunks/row of 128B) on BOTH sides (rule #21).
//  bv kept in registers across both phases. acc/epilogue identical to v4.
// ---------------------------------------------------------------------------
__global__ __launch_bounds__(512, 2)
void mfma_gemm(const u16* __restrict__ A, const u16* __restrict__ W,
               const float* __restrict__ bias,
               const u16* __restrict__ resb,
               float* __restrict__ Cf, u16* __restrict__ Cb,
               int M, int K, int N, int relu, int gx)
{
    __shared__ u16 lds[49152];   // 96 KB: 2 buffers x (A 32KB + B 16KB)
    const int tid = threadIdx.x;
    const int l = tid & 63, w = tid >> 6;     // 8 waves
    const int wm = w >> 1, wn = w & 1;        // 4M x 2N wave grid

    const int nwg = gridDim.x;
    const int q = nwg >> 3, r = nwg & 7;
    const int xcd = blockIdx.x & 7, idx = blockIdx.x >> 3;
    const int lin = (xcd < r ? xcd * (q + 1) : r * (q + 1) + (xcd - r) * q) + idx;
    const int by = lin / gx, bx = lin - by * gx;
    const int rowBase = by * 256, colBase = bx * 128;

    f32x4 acc[4][4];
    #pragma unroll
    for (int m = 0; m < 4; m++)
        #pragma unroll
        for (int n = 0; n < 4; n++) acc[m][n] = 0.f;

    // Staging sources. A: 2048 chunks (4/thread), B: 1024 chunks (2/thread).
    // Physical chunk p of row holds global K-chunk c = p ^ (row&7).
    const u16* gApt[4];
    const u16* gBpt[2];
    #pragma unroll
    for (int i = 0; i < 4; i++) {
        int G = i * 512 + tid;
        int row = G >> 3, p = G & 7;
        int c = p ^ (row & 7);
        int grow = rowBase + row; if (grow > M - 1) grow = M - 1;
        gApt[i] = A + (size_t)grow * K + c * 8;
    }
    #pragma unroll
    for (int i = 0; i < 2; i++) {
        int G = i * 512 + tid;
        int row = G >> 3, p = G & 7;
        int c = p ^ (row & 7);
        gBpt[i] = W + (size_t)(colBase + row) * K + c * 8;
    }

    const int NT = K >> 6;
    // unit0: A chunks 0-1023 + B chunks 0-511 (3 loads); unit1: the rest (3).
    auto STAGE_U0 = [&](int tt) {
        const int kb = tt << 6;
        u16* dA = lds + (tt & 1) * 24576;
        u16* dB = dA + 16384;
        gload16(gApt[0] + kb, dA + (size_t)(0 * 512 + tid) * 8 - l * 8 + l * 8);
        gload16(gApt[1] + kb, dA + (size_t)(1 * 512 + w * 64) * 8);
        gload16(gBpt[0] + kb, dB + (size_t)(0 * 512 + w * 64) * 8);
    };
    auto STAGE_U1 = [&](int tt) {
        const int kb = tt << 6;
        u16* dA = lds + (tt & 1) * 24576;
        u16* dB = dA + 16384;
        gload16(gApt[2] + kb, dA + (size_t)(2 * 512 + w * 64) * 8);
        gload16(gApt[3] + kb, dA + (size_t)(3 * 512 + w * 64) * 8);
        gload16(gBpt[1] + kb, dB + (size_t)(1 * 512 + w * 64) * 8);
    };
    // fix unit0 first dest (wave-uniform base + lane*16):
    // dest for A chunk G = dA + G*8 with G = i*512 + w*64 + l.
    // (the expression above reduces to dA + (0*512 + w*64)*8 for lane base)

    STAGE_U0(0);
    STAGE_U1(0);

    const int g = l >> 4;
    for (int t = 0; t < NT; ++t) {
        const u16* Ab = lds + (t & 1) * 24576;
        const u16* Bb = Ab + 16384;
        if (t + 1 < NT) {
            STAGE_U0(t + 1);
            asm volatile("s_waitcnt vmcnt(3)" ::: "memory");   // tile t fully landed
        } else {
            asm volatile("s_waitcnt vmcnt(0)" ::: "memory");
        }
        __builtin_amdgcn_s_barrier();
        __builtin_amdgcn_sched_barrier(0);

        // ---- phase 0: bv (all) + av rows 0-1; stage unit1(t+1); 16 MFMA ----
        bf16x8 bv[4][2], av0[2][2];
        #pragma unroll
        for (int ks = 0; ks < 2; ks++) {
            #pragma unroll
            for (int fc = 0; fc < 4; fc++) {
                int col = wn * 64 + fc * 16 + (l & 15);
                bv[fc][ks] = *(const bf16x8*)(Bb + col * 64 + (((ks * 4 + g) ^ (col & 7)) * 8));
            }
            #pragma unroll
            for (int fr = 0; fr < 2; fr++) {
                int row = wm * 64 + fr * 16 + (l & 15);
                av0[fr][ks] = *(const bf16x8*)(Ab + row * 64 + (((ks * 4 + g) ^ (row & 7)) * 8));
            }
        }
        if (t + 1 < NT) STAGE_U1(t + 1);
        asm volatile("s_waitcnt lgkmcnt(0)" ::: "memory");
        __builtin_amdgcn_sched_barrier(0);
        __builtin_amdgcn_s_setprio(1);
        #pragma unroll
        for (int ks = 0; ks < 2; ks++)
            #pragma unroll
            for (int m = 0; m < 2; m++)
                #pragma unroll
                for (int n = 0; n < 4; n++)
                    acc[m][n] = __builtin_amdgcn_mfma_f32_16x16x32_bf16(av0[m][ks], bv[n][ks], acc[m][n], 0, 0, 0);
        __builtin_amdgcn_s_setprio(0);
        __builtin_amdgcn_s_barrier();
        __builtin_amdgcn_sched_barrier(0);

        // ---- phase 1: av rows 2-3; 16 MFMA ----
        bf16x8 av1[2][2];
        #pragma unroll
        for (int ks = 0; ks < 2; ks++)
            #pragma unroll
            for (int fr = 0; fr < 2; fr++) {
                int row = wm * 64 + (fr + 2) * 16 + (l & 15);
                av1[fr][ks] = *(const bf16x8*)(Ab + row * 64 + (((ks * 4 + g) ^ (row & 7)) * 8));
            }
        asm volatile("s_waitcnt lgkmcnt(0)" ::: "memory");
        __builtin_amdgcn_sched_barrier(0);
        __builtin_amdgcn_s_setprio(1);
        #pragma unroll
        for (int ks = 0; ks < 2; ks++)
            #pragma unroll
            for (int m = 0; m < 2; m++)
                #pragma unroll
                for (int n = 0; n < 4; n++)
                    acc[m + 2][n] = __builtin_amdgcn_mfma_f32_16x16x32_bf16(av1[m][ks], bv[n][ks], acc[m + 2][n], 0, 0, 0);
        __builtin_amdgcn_s_setprio(0);
        __builtin_amdgcn_s_barrier();      // closing: tile-t reads done before t+2 stages
        __builtin_amdgcn_sched_barrier(0);
    }

    // ---- epilogue: per-wave LDS scratch -> coalesced vector stores ----
    const int cc = colBase + wn * 64 + (l & 15);
    float bs4[4];
    #pragma unroll
    for (int n = 0; n < 4; n++) bs4[n] = bias[cc + n * 16];

    if (Cb) {
        u16* WS = lds + w * 2048;   // 4 KB/wave (32 rows x 64 u16)
        #pragma unroll
        for (int hh = 0; hh < 2; hh++) {
            #pragma unroll
            for (int mi = 0; mi < 2; mi++) {
                #pragma unroll
                for (int n = 0; n < 4; n++) {
                    int colv = n * 16 + (l & 15);
                    #pragma unroll
                    for (int reg = 0; reg < 4; reg++) {
                        int rowh = mi * 16 + (l >> 4) * 4 + reg;
                        float v = acc[hh * 2 + mi][n][reg] + bs4[n];
                        if (relu) v = fmaxf(v, 0.f);
                        WS[rowh * 64 + (colv ^ (((rowh >> 2) & 3) << 4))] = f2bf(v);
                    }
                }
            }
            asm volatile("s_waitcnt lgkmcnt(0)" ::: "memory");
            __builtin_amdgcn_sched_barrier(0);
            #pragma unroll
            for (int j = 0; j < 4; j++) {
                int rowh = (l >> 3) + 8 * j;
                int col8 = (l & 7) * 8;
                int colx = col8 ^ (((rowh >> 2) & 3) << 4);
                uint4 v = *(const uint4*)(WS + rowh * 64 + colx);
                int grow = rowBase + wm * 64 + hh * 32 + rowh;
                if (grow < M)
                    *(uint4*)(Cb + (size_t)grow * N + colBase + wn * 64 + col8) = v;
            }
            asm volatile("s_waitcnt lgkmcnt(0)" ::: "memory");
        }
    } else {
        float* WSf = (float*)lds + w * 1024;   // 4 KB/wave (16 rows x 64 f32)
        #pragma unroll
        for (int hh = 0; hh < 2; hh++) {
            #pragma unroll
            for (int mi = 0; mi < 2; mi++) {
                #pragma unroll
                for (int n = 0; n < 4; n++) {
                    int colv = n * 16 + (l & 15);
                    #pragma unroll
                    for (int reg = 0; reg < 4; reg++) {
                        int rowh = (l >> 4) * 4 + reg;   // 0..15
                        WSf[rowh * 64 + (colv ^ (((rowh >> 2) & 3) << 4))] =
                            acc[hh * 2 + mi][n][reg] + bs4[n];
                    }
                }
                asm volatile("s_waitcnt lgkmcnt(0)" ::: "memory");
                __builtin_amdgcn_sched_barrier(0);
                #pragma unroll
                for (int j = 0; j < 4; j++) {
                    int rowh = (l >> 4) + 4 * j;         // 0..15
                    int col4 = (l & 15) * 4;
                    int colx = col4 ^ (((rowh >> 2) & 3) << 4);
                    float4 v = *(const float4*)(WSf + rowh * 64 + colx);
                    int grow = rowBase + wm * 64 + hh * 32 + mi * 16 + rowh;
                    if (grow < M) {
                        int gcol = colBase + wn * 64 + col4;
                        if (resb) {
                            uint2 rb = *(const uint2*)&resb[(size_t)grow * N + gcol];
                            v.x += bf2f((u16)(rb.x & 0xFFFF));
                            v.y += bf2f((u16)(rb.x >> 16));
                            v.z += bf2f((u16)(rb.y & 0xFFFF));
                            v.w += bf2f((u16)(rb.y >> 16));
                        }
                        if (relu) {
                            v.x = fmaxf(v.x, 0.f); v.y = fmaxf(v.y, 0.f);
                            v.z = fmaxf(v.z, 0.f); v.w = fmaxf(v.w, 0.f);
                        }
                        *(float4*)&Cf[(size_t)grow * N + gcol] = v;
                    }
                }
                asm volatile("s_waitcnt lgkmcnt(0)" ::: "memory");
            }
        }
    }
}

// ---------------------------------------------------------------------------
// Attention (bf16 in/out), unchanged.
// ---------------------------------------------------------------------------
__global__ void attn_kernel(const u16* __restrict__ QKV, const u16* __restrict__ KVs,
                            u16* __restrict__ O)
{
    const int wv   = threadIdx.x >> 6;
    const int lane = threadIdx.x & 63;
    const int b    = blockIdx.x * 4 + wv;
    const int h    = lane >> 3;
    const int d8   = lane & 7;
    const int n = b >> 10, pos = b & 1023;

    float q[8];
    ld8bf(QKV + (size_t)b * 1536 + h * 64 + d8 * 8, q);

    float sc[NSCALES];
    {
        float kk[8];
        ld8bf(QKV + (size_t)b * 1536 + 512 + h * 64 + d8 * 8, kk);
        float p = 0.f;
        #pragma unroll
        for (int j = 0; j < 8; j++) p += q[j] * kk[j];
        p += __shfl_xor(p, 1); p += __shfl_xor(p, 2); p += __shfl_xor(p, 4);
        sc[0] = p * 0.125f;
    }
    {
        int rowOff = 0;
        #pragma unroll
        for (int s = 1; s <= NLEVELS; s++) {
            int Ls = 1024 >> s;
            int row = rowOff + n * Ls + (pos >> s);
            float kk[8];
            ld8bf(KVs + (size_t)row * 1024 + h * 64 + d8 * 8, kk);
            float p = 0.f;
            #pragma unroll
            for (int j = 0; j < 8; j++) p += q[j] * kk[j];
            p += __shfl_xor(p, 1); p += __shfl_xor(p, 2); p += __shfl_xor(p, 4);
            sc[s] = p * 0.125f;
            rowOff += 16 * Ls;
        }
    }
    float m = sc[0];
    #pragma unroll
    for (int s = 1; s < NSCALES; s++) m = fmaxf(m, sc[s]);
    float sum = 0.f;
    #pragma unroll
    for (int s = 0; s < NSCALES; s++) { sc[s] = __expf(sc[s] - m); sum += sc[s]; }
    float inv = 1.f / sum;

    float o[8] = {};
    {
        float vv[8];
        ld8bf(QKV + (size_t)b * 1536 + 1024 + h * 64 + d8 * 8, vv);
        float a = sc[0] * inv;
        #pragma unroll
        for (int j = 0; j < 8; j++) o[j] += a * vv[j];
    }
    {
        int rowOff = 0;
        #pragma unroll
        for (int s = 1; s <= NLEVELS; s++) {
            int Ls = 1024 >> s;
            int row = rowOff + n * Ls + (pos >> s);
            float vv[8];
            ld8bf(KVs + (size_t)row * 1024 + 512 + h * 64 + d8 * 8, vv);
            float a = sc[s] * inv;
            #pragma unroll
            for (int j = 0; j < 8; j++) o[j] += a * vv[j];
            rowOff += 16 * Ls;
        }
    }
    uint4 pk;
    pk.x = (uint32_t)f2bf(o[0]) | ((uint32_t)f2bf(o[1]) << 16);
    pk.y = (uint32_t)f2bf(o[2]) | ((uint32_t)f2bf(o[3]) << 16);
    pk.z = (uint32_t)f2bf(o[4]) | ((uint32_t)f2bf(o[5]) << 16);
    pk.w = (uint32_t)f2bf(o[6]) | ((uint32_t)f2bf(o[7]) << 16);
    *(uint4*)(O + (size_t)b * 512 + h * 64 + d8 * 8) = pk;
}

// ---------------------------------------------------------------------------
// LayerNorm over E=512: one wave per row (4 rows/block), shuffle reduce.
// ---------------------------------------------------------------------------
__global__ void ln_kernel(const float* __restrict__ in, float* __restrict__ out,
                          const float* __restrict__ w, const float* __restrict__ b,
                          u16* __restrict__ out_bf)
{
    const int l = threadIdx.x & 63;
    const int row = blockIdx.x * 4 + (threadIdx.x >> 6);
    const float* p = in + (size_t)row * EE + l * 8;
    float4 v0 = *(const float4*)p;
    float4 v1 = *(const float4*)(p + 4);
    float s  = v0.x + v0.y + v0.z + v0.w + v1.x + v1.y + v1.z + v1.w;
    float s2 = v0.x * v0.x + v0.y * v0.y + v0.z * v0.z + v0.w * v0.w
             + v1.x * v1.x + v1.y * v1.y + v1.z * v1.z + v1.w * v1.w;
    #pragma unroll
    for (int m = 1; m < 64; m <<= 1) { s += __shfl_xor(s, m); s2 += __shfl_xor(s2, m); }
    float mu  = s * (1.f / 512.f);
    float var = s2 * (1.f / 512.f) - mu * mu;
    float rs  = rsqrtf(var + 1e-5f);
    float4 w0 = *(const float4*)&w[l * 8], w1 = *(const float4*)&w[l * 8 + 4];
    float4 b0 = *(const float4*)&b[l * 8], b1 = *(const float4*)&b[l * 8 + 4];
    float o[8];
    o[0] = (v0.x - mu) * rs * w0.x + b0.x;
    o[1] = (v0.y - mu) * rs * w0.y + b0.y;
    o[2] = (v0.z - mu) * rs * w0.z + b0.z;
    o[3] = (v0.w - mu) * rs * w0.w + b0.w;
    o[4] = (v1.x - mu) * rs * w1.x + b1.x;
    o[5] = (v1.y - mu) * rs * w1.y + b1.y;
    o[6] = (v1.z - mu) * rs * w1.z + b1.z;
    o[7] = (v1.w - mu) * rs * w1.w + b1.w;
    float* po = out + (size_t)row * EE + l * 8;
    *(float4*)po       = make_float4(o[0], o[1], o[2], o[3]);
    *(float4*)(po + 4) = make_float4(o[4], o[5], o[6], o[7]);
    if (out_bf) {
        uint4 pk;
        pk.x = (uint32_t)f2bf(o[0]) | ((uint32_t)f2bf(o[1]) << 16);
        pk.y = (uint32_t)f2bf(o[2]) | ((uint32_t)f2bf(o[3]) << 16);
        pk.z = (uint32_t)f2bf(o[4]) | ((uint32_t)f2bf(o[5]) << 16);
        pk.w = (uint32_t)f2bf(o[6]) | ((uint32_t)f2bf(o[7]) << 16);
        *(uint4*)(out_bf + (size_t)row * EE + l * 8) = pk;
    }
}

// ---------------------------------------------------------------------------
extern "C" void kernel_launch(void* const* d_in, const int* in_sizes, int n_in,
                              void* d_out, int out_size, void* d_ws, size_t ws_size,
                              hipStream_t stream)
{
    const float* src        = (const float*)d_in[0];
    const float* conv_w     = (const float*)d_in[1];
    const float* conv_b     = (const float*)d_in[2];
    const float* in_proj_w  = (const float*)d_in[3];
    const float* in_proj_b  = (const float*)d_in[4];
    const float* out_proj_w = (const float*)d_in[5];
    const float* out_proj_b = (const float*)d_in[6];
    const float* ln1_w      = (const float*)d_in[7];
    const float* ln1_b      = (const float*)d_in[8];
    const float* ln2_w      = (const float*)d_in[9];
    const float* ln2_b      = (const float*)d_in[10];
    const float* w1         = (const float*)d_in[11];
    const float* b1         = (const float*)d_in[12];
    const float* w2         = (const float*)d_in[13];
    const float* b2         = (const float*)d_in[14];

    char*  wsb    = (char*)d_ws;
    float* out    = (float*)d_out;
    u16*   src_bf = (u16*)(wsb + B_SRCBF);
    u16*   lvl_bf = (u16*)(wsb + B_LVLBF);
    u16*   QKV    = (u16*)(wsb + B_QKV);
    u16*   KVs    = (u16*)(wsb + B_KVS);
    u16*   O_bf   = (u16*)(wsb + B_OBF);
    float* X      = (float*)(wsb + B_X);
    u16*   X_bf   = (u16*)(wsb + B_XBF);
    u16*   inw_bf = (u16*)(wsb + B_WBF);
    u16*   outw_bf= inw_bf + 786432;
    u16*   w1_bf  = outw_bf + 262144;
    u16*   w2_bf  = w1_bf + 1048576;
    u16*   cw_bf  = w2_bf + 1048576;
    u16*   FFH    = (u16*)(wsb + B_FFH);

    // 0) cast src + weights to bf16 (+ conv_w repack)
    cast_all_kernel<<<11344, 256, 0, stream>>>(src, in_proj_w, out_proj_w, w1, w2, conv_w,
                                               src_bf, inw_bf, outw_bf, w1_bf, w2_bf, cw_bf);

    // 1) conv pyramid: levels 1..8 in one launch, 9..10 in a tiny tail
    conv_chain_kernel<<<NB * NHEADS * 4, 256, 0, stream>>>(src_bf, lvl_bf, cw_bf, conv_b);
    conv_tail_kernel<<<NB * NHEADS, 256, 0, stream>>>(lvl_bf, cw_bf, conv_b);

    // 2) QKV = src_bf @ in_proj_w^T + b  (16384 x 1536), grid 64 x 12
    mfma_gemm<<<64 * 12, 512, 0, stream>>>(
        src_bf, inw_bf, in_proj_b, nullptr, nullptr, QKV, BROWS, EE, 1536, 0, 12);

    // 3) KVs = lvl_bf @ Wkv^T + b_kv  (16368 x 1024), grid 64 x 8
    mfma_gemm<<<64 * 8, 512, 0, stream>>>(
        lvl_bf, inw_bf + (size_t)512 * 512, in_proj_b + 512, nullptr, nullptr, KVs,
        16368, EE, 1024, 0, 8);

    // 4) attention -> O_bf
    attn_kernel<<<BROWS / 4, 256, 0, stream>>>(QKV, KVs, O_bf);

    // 5) X = O_bf @ out_proj^T + b  (fp32), grid 64 x 4
    mfma_gemm<<<64 * 4, 512, 0, stream>>>(
        O_bf, outw_bf, out_proj_b, nullptr, X, nullptr, BROWS, EE, EE, 0, 4);

    // 6) LN1 in place (+ bf16 copy)
    ln_kernel<<<BROWS / 4, 256, 0, stream>>>(X, X, ln1_w, ln1_b, X_bf);

    // 7) FFH = relu(X_bf @ w1^T + b1)  (bf16), grid 64 x 16
    mfma_gemm<<<64 * 16, 512, 0, stream>>>(
        X_bf, w1_bf, b1, nullptr, nullptr, FFH, BROWS, EE, DFF, 1, 16);

    // 8) out = FFH @ w2^T + b2 + X_bf  (fp32 out, bf16 residual), grid 64 x 4
    mfma_gemm<<<64 * 4, 512, 0, stream>>>(
        FFH, w2_bf, b2, X_bf, out, nullptr, BROWS, DFF, EE, 0, 4);

    // 9) LN2 in place on out
    ln_kernel<<<BROWS / 4, 256, 0, stream>>>(out, out, ln2_w, ln2_b, nullptr);
}

// Round 12
// 252.177 us; speedup vs baseline: 1.0058x; 1.0058x over previous
//
#include <hip/hip_runtime.h>
#include <hip/hip_bf16.h>
#include <stdint.h>
#include <math.h>

// Problem constants
#define NB      16
#define LL      1024
#define EE      512
#define NHEADS  8
#define DFF     2048
#define NLEVELS 10
#define NSCALES 11
#define BROWS   (NB * LL)       // 16384

typedef unsigned short u16;
typedef __attribute__((ext_vector_type(8))) short bf16x8;   // 8 bf16 = 4 VGPRs (MFMA A/B frag)
typedef __attribute__((ext_vector_type(4))) float f32x4;    // MFMA C/D frag

// ---------------- workspace layout (byte offsets) ----------------
static const size_t B_SRCBF = 0;                         // 16,777,216
static const size_t B_LVLBF = 16777216;                  // 16,760,832
static const size_t B_QKV   = 33538048;                  // 50,331,648
static const size_t B_KVS   = 83869696;                  // 33,521,664
static const size_t B_OBF   = 117391360;                 // 16,777,216
static const size_t B_X     = 134168576;                 // 33,554,432
static const size_t B_XBF   = 167723008;                 // 16,777,216
static const size_t B_WBF   = 184500224;                 // weights
static const size_t B_FFH   = 0;                         // overlaps dead-by-then buffers

// ---------------- helpers ----------------
__device__ __forceinline__ u16 f2bf(float x) {
    union { float f; uint32_t u; } c; c.f = x;
    uint32_t u = c.u + 0x7FFFu + ((c.u >> 16) & 1u);
    return (u16)(u >> 16);
}
__device__ __forceinline__ float bf2f(u16 v) {
    union { uint32_t u; float f; } c; c.u = ((uint32_t)v) << 16; return c.f;
}
__device__ __forceinline__ void ld8bf(const u16* p, float* f) {
    uint4 r = *(const uint4*)p;
    uint32_t ws[4] = { r.x, r.y, r.z, r.w };
    #pragma unroll
    for (int j = 0; j < 4; j++) {
        union { uint32_t u; float g; } lo, hi;
        lo.u = ws[j] << 16; hi.u = ws[j] & 0xFFFF0000u;
        f[2 * j] = lo.g; f[2 * j + 1] = hi.g;
    }
}
__device__ __forceinline__ void gload16(const u16* g, u16* l) {
    __builtin_amdgcn_global_load_lds(
        (const __attribute__((address_space(1))) void*)g,
        (__attribute__((address_space(3))) void*)l, 16, 0, 0);
}

// ---------------------------------------------------------------------------
// Fused cast kernel: src + 4 weight tensors -> bf16, plus conv_w repack.
// ---------------------------------------------------------------------------
__global__ void cast_all_kernel(const float* __restrict__ s0, const float* __restrict__ s1,
                                const float* __restrict__ s2, const float* __restrict__ s3,
                                const float* __restrict__ s4, const float* __restrict__ cw,
                                u16* __restrict__ d0, u16* __restrict__ d1,
                                u16* __restrict__ d2, u16* __restrict__ d3,
                                u16* __restrict__ d4, u16* __restrict__ dw)
{
    int bid = blockIdx.x;
    if (bid >= 11264) {   // conv_w repack: 81920 outputs
        int base = (bid - 11264) * 1024 + threadIdx.x * 4;
        #pragma unroll
        for (int j = 0; j < 4; j++) {
            int idx = base + j;
            int lvl = idx >> 13, rem = idx & 8191;
            int o = rem >> 7, ck = rem & 127;
            int k = ck >> 6, ci = ck & 63;
            dw[idx] = f2bf(cw[(lvl << 13) + (o << 7) + (ci << 1) + k]);
        }
        return;
    }
    const float* s; u16* d; int nt;
    if      (bid < 8192)  { s = s0; d = d0; nt = 2097152; }
    else if (bid < 8960)  { bid -= 8192;  s = s1; d = d1; nt = 196608; }
    else if (bid < 9216)  { bid -= 8960;  s = s2; d = d2; nt = 65536;  }
    else if (bid < 10240) { bid -= 9216;  s = s3; d = d3; nt = 262144; }
    else                  { bid -= 10240; s = s4; d = d4; nt = 262144; }
    int i = bid * 256 + threadIdx.x;
    if (i < nt) {
        float4 v = ((const float4*)s)[i];
        uint2 o;
        o.x = (uint32_t)f2bf(v.x) | ((uint32_t)f2bf(v.y) << 16);
        o.y = (uint32_t)f2bf(v.z) | ((uint32_t)f2bf(v.w) << 16);
        ((uint2*)d)[i] = o;
    }
}

// ---------------------------------------------------------------------------
// Conv chain kernel: levels 1..8 in ONE launch (unchanged).
// ---------------------------------------------------------------------------
__global__ __launch_bounds__(256, 2)
void conv_chain_kernel(const u16* __restrict__ src_bf, u16* __restrict__ lvl_bf,
                       const u16* __restrict__ cw, const float* __restrict__ cb)
{
    __shared__ u16 BIG[16384];   // 32KB
    __shared__ u16 MID[8192];    // 16KB
    __shared__ u16 WB[8192];     // 16KB: per-level weights [o][128]
    const int tid = threadIdx.x;
    const int l = tid & 63, w = tid >> 6;
    const int bid = blockIdx.x;          // n*32 + h*4 + q
    const int q  = bid & 3;
    const int h  = (bid >> 2) & 7;
    const int n  = bid >> 5;

    {
        const u16* base = src_bf + ((size_t)n * 1024 + q * 256) * 512 + h * 64;
        #pragma unroll
        for (int j = 0; j < 8; j++) {
            int c = j * 256 + w * 64 + l;
            int row = c >> 3, lch = c & 7;
            int gch = lch ^ (row & 7);
            gload16(base + (size_t)row * 512 + gch * 8,
                    BIG + (size_t)(j * 256 + w * 64) * 8);
        }
    }

    const u16* IN = BIG;
    u16* OUTb = MID;
    int R = 128;
    int T = 512;
    size_t rowOff = 0;
    for (int lvl = 1; lvl <= 8; lvl++) {
        {
            const u16* wsrc = cw + (size_t)(lvl - 1) * 8192;
            #pragma unroll
            for (int j = 0; j < 4; j++) {
                int c = j * 256 + w * 64 + l;
                int o = c >> 4, lch = c & 15;
                int gch = lch ^ (o & 7);
                gload16(wsrc + o * 128 + gch * 8, WB + (size_t)(j * 256 + w * 64) * 8);
            }
        }
        asm volatile("s_waitcnt vmcnt(0)" ::: "memory");
        __syncthreads();

        const int nrt = (R + 15) >> 4;
        const int maxil = 2 * R - 1;
        for (int f = w; f < nrt * 4; f += 4) {
            int rt = f >> 2, nc = f & 3;
            int o = nc * 16 + (l & 15);
            f32x4 acc = {0.f, 0.f, 0.f, 0.f};
            #pragma unroll
            for (int s = 0; s < 4; s++) {
                int il = 2 * (rt * 16 + (l & 15)) + (s >> 1);
                if (il > maxil) il = maxil;
                int ach = (((s & 1) * 4) + (l >> 4)) ^ (il & 7);
                bf16x8 av = *(const bf16x8*)(IN + il * 64 + ach * 8);
                int bch = (s * 4 + (l >> 4)) ^ (o & 7);
                bf16x8 bv = *(const bf16x8*)(WB + o * 128 + bch * 8);
                acc = __builtin_amdgcn_mfma_f32_16x16x32_bf16(av, bv, acc, 0, 0, 0);
            }
            float bb = cb[(lvl - 1) * 64 + o];
            #pragma unroll
            for (int reg = 0; reg < 4; reg++) {
                int rloc = rt * 16 + (l >> 4) * 4 + reg;
                if (rloc < R) {
                    float v = fmaxf(acc[reg] + bb, 0.f);
                    u16 b16 = f2bf(v);
                    lvl_bf[(rowOff + (size_t)n * T + (size_t)q * R + rloc) * 512 + h * 64 + o] = b16;
                    OUTb[rloc * 64 + (((o >> 3) ^ (rloc & 7)) << 3) + (o & 7)] = b16;
                }
            }
        }
        __syncthreads();
        const u16* tmp = IN; IN = OUTb; OUTb = (u16*)tmp;
        rowOff += (size_t)16 * T;
        T >>= 1; R >>= 1;
    }
}

// ---------------------------------------------------------------------------
// Conv tail: levels 9 and 10 (tiny). Block per (n,h).
// ---------------------------------------------------------------------------
__global__ void conv_tail_kernel(u16* __restrict__ lvl_bf, const u16* __restrict__ cw,
                                 const float* __restrict__ cb)
{
    const int h = blockIdx.x & 7, n = blockIdx.x >> 3;
    const int tid = threadIdx.x;
    __shared__ float L8s[4][64];
    __shared__ float L9s[2][64];
    {
        int r = tid >> 6, c = tid & 63;
        L8s[r][c] = bf2f(lvl_bf[((size_t)16256 + n * 4 + r) * 512 + h * 64 + c]);
    }
    __syncthreads();
    if (tid < 128) {
        int t = tid >> 6, o = tid & 63;
        const u16* wr = cw + (size_t)8 * 8192 + o * 128;
        float acc = cb[8 * 64 + o];
        #pragma unroll
        for (int k = 0; k < 2; k++)
            #pragma unroll 16
            for (int ci = 0; ci < 64; ci++)
                acc += L8s[2 * t + k][ci] * bf2f(wr[k * 64 + ci]);
        acc = fmaxf(acc, 0.f);
        L9s[t][o] = acc;
        lvl_bf[((size_t)16320 + n * 2 + t) * 512 + h * 64 + o] = f2bf(acc);
    }
    __syncthreads();
    if (tid < 64) {
        int o = tid;
        const u16* wr = cw + (size_t)9 * 8192 + o * 128;
        float acc = cb[9 * 64 + o];
        #pragma unroll
        for (int k = 0; k < 2; k++)
            #pragma unroll 16
            for (int ci = 0; ci < 64; ci++)
                acc += L9s[k][ci] * bf2f(wr[k * 64 + ci]);
        acc = fmaxf(acc, 0.f);
        lvl_bf[((size_t)16352 + n) * 512 + h * 64 + o] = f2bf(acc);
    }
}

// ---------------------------------------------------------------------------
// bf16 MFMA GEMM v4 (round-10 proven, for N=512 shapes): 256x128, BK=32,
// 8 waves, 3-ring 72KB, single barrier/iter, involution swizzle, setprio.
// ---------------------------------------------------------------------------
__global__ __launch_bounds__(512, 4)
void mfma_gemm(const u16* __restrict__ A, const u16* __restrict__ W,
               const float* __restrict__ bias,
               const u16* __restrict__ resb,
               float* __restrict__ Cf, u16* __restrict__ Cb,
               int M, int K, int N, int relu, int gx)
{
    __shared__ u16 lds[36864];   // 72 KB: 3 buffers x (A 16KB + B 8KB)
    const int tid = threadIdx.x;
    const int l = tid & 63, w = tid >> 6;     // 8 waves
    const int wm = w >> 1, wn = w & 1;        // 4M x 2N wave grid

    const int nwg = gridDim.x;
    const int q = nwg >> 3, r = nwg & 7;
    const int xcd = blockIdx.x & 7, idx = blockIdx.x >> 3;
    const int lin = (xcd < r ? xcd * (q + 1) : r * (q + 1) + (xcd - r) * q) + idx;
    const int by = lin / gx, bx = lin - by * gx;
    const int rowBase = by * 256, colBase = bx * 128;

    f32x4 acc[4][4];
    #pragma unroll
    for (int m = 0; m < 4; m++)
        #pragma unroll
        for (int n = 0; n < 4; n++) acc[m][n] = 0.f;

    const u16* gApt[2];
    const u16* gBpt;
    #pragma unroll
    for (int i = 0; i < 2; i++) {
        int G = i * 512 + tid;
        int row = G >> 2, p = G & 3;
        int c = p ^ ((row >> 1) & 3);
        int grow = rowBase + row; if (grow > M - 1) grow = M - 1;
        gApt[i] = A + (size_t)grow * K + c * 8;
    }
    {
        int G = tid;
        int row = G >> 2, p = G & 3;
        int c = p ^ ((row >> 1) & 3);
        gBpt = W + (size_t)(colBase + row) * K + c * 8;
    }

    const int NT = K >> 5;
    auto STAGE = [&](int tt, int buf) {
        const int kb = tt << 5;
        u16* dA = lds + buf * 12288;
        u16* dB = dA + 8192;
        gload16(gApt[0] + kb, dA + (size_t)(w * 64) * 8);
        gload16(gApt[1] + kb, dA + (size_t)(512 + w * 64) * 8);
        gload16(gBpt + kb, dB + (size_t)(w * 64) * 8);
    };
    STAGE(0, 0);
    if (NT > 1) STAGE(1, 1);

    int cbuf = 0, sbuf = 2;
    for (int t = 0; t < NT; ++t) {
        if (t + 1 < NT) asm volatile("s_waitcnt vmcnt(3)" ::: "memory");
        else            asm volatile("s_waitcnt vmcnt(0)" ::: "memory");
        __builtin_amdgcn_s_barrier();
        __builtin_amdgcn_sched_barrier(0);
        if (t + 2 < NT) STAGE(t + 2, sbuf);

        const u16* Ab = lds + cbuf * 12288;
        const u16* Bb = Ab + 8192;
        const int c = l >> 4;
        bf16x8 av[4], bv[4];
        #pragma unroll
        for (int fr = 0; fr < 4; fr++) {
            int row = wm * 64 + fr * 16 + (l & 15);
            av[fr] = *(const bf16x8*)(Ab + row * 32 + ((c ^ ((row >> 1) & 3)) * 8));
        }
        #pragma unroll
        for (int fc = 0; fc < 4; fc++) {
            int col = wn * 64 + fc * 16 + (l & 15);
            bv[fc] = *(const bf16x8*)(Bb + col * 32 + ((c ^ ((col >> 1) & 3)) * 8));
        }
        asm volatile("s_waitcnt lgkmcnt(0)" ::: "memory");
        __builtin_amdgcn_sched_barrier(0);
        __builtin_amdgcn_s_setprio(1);
        #pragma unroll
        for (int m = 0; m < 4; m++)
            #pragma unroll
            for (int n = 0; n < 4; n++)
                acc[m][n] = __builtin_amdgcn_mfma_f32_16x16x32_bf16(av[m], bv[n], acc[m][n], 0, 0, 0);
        __builtin_amdgcn_s_setprio(0);

        cbuf = (cbuf == 2) ? 0 : cbuf + 1;
        sbuf = (sbuf == 2) ? 0 : sbuf + 1;
    }
    __builtin_amdgcn_s_barrier();
    __builtin_amdgcn_sched_barrier(0);

    const int cc = colBase + wn * 64 + (l & 15);
    float bs4[4];
    #pragma unroll
    for (int n = 0; n < 4; n++) bs4[n] = bias[cc + n * 16];

    if (Cb) {
        u16* WS = lds + w * 2048;
        #pragma unroll
        for (int hh = 0; hh < 2; hh++) {
            #pragma unroll
            for (int mi = 0; mi < 2; mi++) {
                #pragma unroll
                for (int n = 0; n < 4; n++) {
                    int colv = n * 16 + (l & 15);
                    #pragma unroll
                    for (int reg = 0; reg < 4; reg++) {
                        int rowh = mi * 16 + (l >> 4) * 4 + reg;
                        float v = acc[hh * 2 + mi][n][reg] + bs4[n];
                        if (relu) v = fmaxf(v, 0.f);
                        WS[rowh * 64 + (colv ^ (((rowh >> 2) & 3) << 4))] = f2bf(v);
                    }
                }
            }
            asm volatile("s_waitcnt lgkmcnt(0)" ::: "memory");
            __builtin_amdgcn_sched_barrier(0);
            #pragma unroll
            for (int j = 0; j < 4; j++) {
                int rowh = (l >> 3) + 8 * j;
                int col8 = (l & 7) * 8;
                int colx = col8 ^ (((rowh >> 2) & 3) << 4);
                uint4 v = *(const uint4*)(WS + rowh * 64 + colx);
                int grow = rowBase + wm * 64 + hh * 32 + rowh;
                if (grow < M)
                    *(uint4*)(Cb + (size_t)grow * N + colBase + wn * 64 + col8) = v;
            }
            asm volatile("s_waitcnt lgkmcnt(0)" ::: "memory");
        }
    } else {
        float* WSf = (float*)lds + w * 1024;
        #pragma unroll
        for (int hh = 0; hh < 2; hh++) {
            #pragma unroll
            for (int mi = 0; mi < 2; mi++) {
                #pragma unroll
                for (int n = 0; n < 4; n++) {
                    int colv = n * 16 + (l & 15);
                    #pragma unroll
                    for (int reg = 0; reg < 4; reg++) {
                        int rowh = (l >> 4) * 4 + reg;
                        WSf[rowh * 64 + (colv ^ (((rowh >> 2) & 3) << 4))] =
                            acc[hh * 2 + mi][n][reg] + bs4[n];
                    }
                }
                asm volatile("s_waitcnt lgkmcnt(0)" ::: "memory");
                __builtin_amdgcn_sched_barrier(0);
                #pragma unroll
                for (int j = 0; j < 4; j++) {
                    int rowh = (l >> 4) + 4 * j;
                    int col4 = (l & 15) * 4;
                    int colx = col4 ^ (((rowh >> 2) & 3) << 4);
                    float4 v = *(const float4*)(WSf + rowh * 64 + colx);
                    int grow = rowBase + wm * 64 + hh * 32 + mi * 16 + rowh;
                    if (grow < M) {
                        int gcol = colBase + wn * 64 + col4;
                        if (resb) {
                            uint2 rb = *(const uint2*)&resb[(size_t)grow * N + gcol];
                            v.x += bf2f((u16)(rb.x & 0xFFFF));
                            v.y += bf2f((u16)(rb.x >> 16));
                            v.z += bf2f((u16)(rb.y & 0xFFFF));
                            v.w += bf2f((u16)(rb.y >> 16));
                        }
                        if (relu) {
                            v.x = fmaxf(v.x, 0.f); v.y = fmaxf(v.y, 0.f);
                            v.z = fmaxf(v.z, 0.f); v.w = fmaxf(v.w, 0.f);
                        }
                        *(float4*)&Cf[(size_t)grow * N + gcol] = v;
                    }
                }
                asm volatile("s_waitcnt lgkmcnt(0)" ::: "memory");
            }
        }
    }
}

// ---------------------------------------------------------------------------
// bf16 MFMA GEMM v6 (m201 geometry, for N%256==0 shapes): 256x256 tile,
// BK=64, 8 waves (2M x 4N), per-wave 128x64 (acc[8][4]).
//  - 2-buffer LDS 128KB; 1 block/CU, 2 waves/SIMD.
//  - per tile: ONE {vmcnt(0); barrier} at entry (exact counted wait: the only
//    outstanding loads at that point ARE tile t's 8) + 4 quadrant phases,
//    each {4 ds_reads (av) [+8 bv at p0] ; stage 1 half-tile of t+1 ;
//    lgkmcnt(0) ; setprio(1) 16 MFMA setprio(0)} separated by sched_barrier.
//  - LDS reads/MFMA = 24/64 = 0.375 (vs 0.5 in v4).
//  - involution swizzle p = c ^ (row&7) on 8-chunk 128B rows (both sides).
// ---------------------------------------------------------------------------
__global__ __launch_bounds__(512, 2)
void mfma_gemm_big(const u16* __restrict__ A, const u16* __restrict__ W,
                   const float* __restrict__ bias, u16* __restrict__ Cb,
                   int M, int K, int N, int relu, int gx)
{
    __shared__ u16 lds[65536];   // 128 KB: 2 buf x (A 32KB + B 32KB)
    const int tid = threadIdx.x;
    const int l = tid & 63, w = tid >> 6;     // 8 waves
    const int wm = w >> 2, wn = w & 3;        // 2M x 4N; per-wave 128x64

    const int nwg = gridDim.x;
    const int q = nwg >> 3, r = nwg & 7;
    const int xcd = blockIdx.x & 7, idx = blockIdx.x >> 3;
    const int lin = (xcd < r ? xcd * (q + 1) : r * (q + 1) + (xcd - r) * q) + idx;
    const int by = lin / gx, bx = lin - by * gx;
    const int rowBase = by * 256, colBase = bx * 256;

    f32x4 acc[8][4];
    #pragma unroll
    for (int m = 0; m < 8; m++)
        #pragma unroll
        for (int n = 0; n < 4; n++) acc[m][n] = 0.f;

    // Staging pointers: A and B each 2048 chunks (16B), 4/thread.
    // Physical chunk p of row holds global K-chunk c = p ^ (row&7).
    const u16* gApt[4];
    const u16* gBpt[4];
    #pragma unroll
    for (int j = 0; j < 4; j++) {
        int G = j * 512 + tid;
        int row = G >> 3, p = G & 7;
        int c = p ^ (row & 7);
        int grow = rowBase + row; if (grow > M - 1) grow = M - 1;
        gApt[j] = A + (size_t)grow * K + c * 8;
        gBpt[j] = W + (size_t)(colBase + row) * K + c * 8;   // N%256==0: in-bounds
    }

    const int NT = K >> 6;
    auto STAGE = [&](int tt, int unit) {   // unit 0,1 = A halves; 2,3 = B halves
        const int kb = tt << 6;
        u16* base = lds + (tt & 1) * 32768;
        if (unit < 2) {
            gload16(gApt[unit * 2]     + kb, base + (size_t)((unit * 2)     * 512 + w * 64) * 8);
            gload16(gApt[unit * 2 + 1] + kb, base + (size_t)((unit * 2 + 1) * 512 + w * 64) * 8);
        } else {
            int u = unit - 2;
            gload16(gBpt[u * 2]     + kb, base + 16384 + (size_t)((u * 2)     * 512 + w * 64) * 8);
            gload16(gBpt[u * 2 + 1] + kb, base + 16384 + (size_t)((u * 2 + 1) * 512 + w * 64) * 8);
        }
    };
    STAGE(0, 0); STAGE(0, 1); STAGE(0, 2); STAGE(0, 3);

    const int g = l >> 4;
    for (int t = 0; t < NT; ++t) {
        // exact counted wait: outstanding = tile t's 8 loads only
        asm volatile("s_waitcnt vmcnt(0)" ::: "memory");
        __builtin_amdgcn_s_barrier();
        __builtin_amdgcn_sched_barrier(0);
        const u16* Ab = lds + (t & 1) * 32768;
        const u16* Bb = Ab + 16384;

        bf16x8 bv[4][2];
        #pragma unroll
        for (int p = 0; p < 4; ++p) {
            bf16x8 av[2][2];
            #pragma unroll
            for (int ks = 0; ks < 2; ks++) {
                #pragma unroll
                for (int fr = 0; fr < 2; fr++) {
                    int row = wm * 128 + (p * 2 + fr) * 16 + (l & 15);
                    av[fr][ks] = *(const bf16x8*)(Ab + row * 64 + (((ks * 4 + g) ^ (row & 7)) * 8));
                }
                if (p == 0) {
                    #pragma unroll
                    for (int fc = 0; fc < 4; fc++) {
                        int col = wn * 64 + fc * 16 + (l & 15);
                        bv[fc][ks] = *(const bf16x8*)(Bb + col * 64 + (((ks * 4 + g) ^ (col & 7)) * 8));
                    }
                }
            }
            if (t + 1 < NT) STAGE(t + 1, p);     // writes opposite buffer; safe
            asm volatile("s_waitcnt lgkmcnt(0)" ::: "memory");
            __builtin_amdgcn_sched_barrier(0);
            __builtin_amdgcn_s_setprio(1);
            #pragma unroll
            for (int ks = 0; ks < 2; ks++)
                #pragma unroll
                for (int fr = 0; fr < 2; fr++)
                    #pragma unroll
                    for (int fc = 0; fc < 4; fc++)
                        acc[p * 2 + fr][fc] = __builtin_amdgcn_mfma_f32_16x16x32_bf16(
                            av[fr][ks], bv[fc][ks], acc[p * 2 + fr][fc], 0, 0, 0);
            __builtin_amdgcn_s_setprio(0);
            __builtin_amdgcn_sched_barrier(0);
        }
    }
    __builtin_amdgcn_s_barrier();   // protect epilogue scratch (overlaps buffers)
    __builtin_amdgcn_sched_barrier(0);

    // ---- epilogue: per-wave LDS scratch -> coalesced bf16 stores ----
    const int cc = colBase + wn * 64 + (l & 15);
    float bs4[4];
    #pragma unroll
    for (int n = 0; n < 4; n++) bs4[n] = bias[cc + n * 16];

    u16* WS = lds + w * 2048;   // 4 KB/wave: 32 rows x 64 u16
    #pragma unroll
    for (int grp = 0; grp < 4; grp++) {
        #pragma unroll
        for (int mi = 0; mi < 2; mi++) {
            int mf = grp * 2 + mi;
            #pragma unroll
            for (int n = 0; n < 4; n++) {
                int colv = n * 16 + (l & 15);
                #pragma unroll
                for (int reg = 0; reg < 4; reg++) {
                    int rowh = mi * 16 + (l >> 4) * 4 + reg;
                    float v = acc[mf][n][reg] + bs4[n];
                    if (relu) v = fmaxf(v, 0.f);
                    WS[rowh * 64 + (colv ^ (((rowh >> 2) & 3) << 4))] = f2bf(v);
                }
            }
        }
        asm volatile("s_waitcnt lgkmcnt(0)" ::: "memory");
        __builtin_amdgcn_sched_barrier(0);
        #pragma unroll
        for (int j = 0; j < 4; j++) {
            int rowh = (l >> 3) + 8 * j;
            int col8 = (l & 7) * 8;
            int colx = col8 ^ (((rowh >> 2) & 3) << 4);
            uint4 v = *(const uint4*)(WS + rowh * 64 + colx);
            int grow = rowBase + wm * 128 + grp * 32 + rowh;
            if (grow < M)
                *(uint4*)(Cb + (size_t)grow * N + colBase + wn * 64 + col8) = v;
        }
        asm volatile("s_waitcnt lgkmcnt(0)" ::: "memory");
    }
}

// ---------------------------------------------------------------------------
// Attention (bf16 in/out), unchanged.
// ---------------------------------------------------------------------------
__global__ void attn_kernel(const u16* __restrict__ QKV, const u16* __restrict__ KVs,
                            u16* __restrict__ O)
{
    const int wv   = threadIdx.x >> 6;
    const int lane = threadIdx.x & 63;
    const int b    = blockIdx.x * 4 + wv;
    const int h    = lane >> 3;
    const int d8   = lane & 7;
    const int n = b >> 10, pos = b & 1023;

    float q[8];
    ld8bf(QKV + (size_t)b * 1536 + h * 64 + d8 * 8, q);

    float sc[NSCALES];
    {
        float kk[8];
        ld8bf(QKV + (size_t)b * 1536 + 512 + h * 64 + d8 * 8, kk);
        float p = 0.f;
        #pragma unroll
        for (int j = 0; j < 8; j++) p += q[j] * kk[j];
        p += __shfl_xor(p, 1); p += __shfl_xor(p, 2); p += __shfl_xor(p, 4);
        sc[0] = p * 0.125f;
    }
    {
        int rowOff = 0;
        #pragma unroll
        for (int s = 1; s <= NLEVELS; s++) {
            int Ls = 1024 >> s;
            int row = rowOff + n * Ls + (pos >> s);
            float kk[8];
            ld8bf(KVs + (size_t)row * 1024 + h * 64 + d8 * 8, kk);
            float p = 0.f;
            #pragma unroll
            for (int j = 0; j < 8; j++) p += q[j] * kk[j];
            p += __shfl_xor(p, 1); p += __shfl_xor(p, 2); p += __shfl_xor(p, 4);
            sc[s] = p * 0.125f;
            rowOff += 16 * Ls;
        }
    }
    float m = sc[0];
    #pragma unroll
    for (int s = 1; s < NSCALES; s++) m = fmaxf(m, sc[s]);
    float sum = 0.f;
    #pragma unroll
    for (int s = 0; s < NSCALES; s++) { sc[s] = __expf(sc[s] - m); sum += sc[s]; }
    float inv = 1.f / sum;

    float o[8] = {};
    {
        float vv[8];
        ld8bf(QKV + (size_t)b * 1536 + 1024 + h * 64 + d8 * 8, vv);
        float a = sc[0] * inv;
        #pragma unroll
        for (int j = 0; j < 8; j++) o[j] += a * vv[j];
    }
    {
        int rowOff = 0;
        #pragma unroll
        for (int s = 1; s <= NLEVELS; s++) {
            int Ls = 1024 >> s;
            int row = rowOff + n * Ls + (pos >> s);
            float vv[8];
            ld8bf(KVs + (size_t)row * 1024 + 512 + h * 64 + d8 * 8, vv);
            float a = sc[s] * inv;
            #pragma unroll
            for (int j = 0; j < 8; j++) o[j] += a * vv[j];
            rowOff += 16 * Ls;
        }
    }
    uint4 pk;
    pk.x = (uint32_t)f2bf(o[0]) | ((uint32_t)f2bf(o[1]) << 16);
    pk.y = (uint32_t)f2bf(o[2]) | ((uint32_t)f2bf(o[3]) << 16);
    pk.z = (uint32_t)f2bf(o[4]) | ((uint32_t)f2bf(o[5]) << 16);
    pk.w = (uint32_t)f2bf(o[6]) | ((uint32_t)f2bf(o[7]) << 16);
    *(uint4*)(O + (size_t)b * 512 + h * 64 + d8 * 8) = pk;
}

// ---------------------------------------------------------------------------
// LayerNorm over E=512: one wave per row (4 rows/block), shuffle reduce.
// ---------------------------------------------------------------------------
__global__ void ln_kernel(const float* __restrict__ in, float* __restrict__ out,
                          const float* __restrict__ w, const float* __restrict__ b,
                          u16* __restrict__ out_bf)
{
    const int l = threadIdx.x & 63;
    const int row = blockIdx.x * 4 + (threadIdx.x >> 6);
    const float* p = in + (size_t)row * EE + l * 8;
    float4 v0 = *(const float4*)p;
    float4 v1 = *(const float4*)(p + 4);
    float s  = v0.x + v0.y + v0.z + v0.w + v1.x + v1.y + v1.z + v1.w;
    float s2 = v0.x * v0.x + v0.y * v0.y + v0.z * v0.z + v0.w * v0.w
             + v1.x * v1.x + v1.y * v1.y + v1.z * v1.z + v1.w * v1.w;
    #pragma unroll
    for (int m = 1; m < 64; m <<= 1) { s += __shfl_xor(s, m); s2 += __shfl_xor(s2, m); }
    float mu  = s * (1.f / 512.f);
    float var = s2 * (1.f / 512.f) - mu * mu;
    float rs  = rsqrtf(var + 1e-5f);
    float4 w0 = *(const float4*)&w[l * 8], w1 = *(const float4*)&w[l * 8 + 4];
    float4 b0 = *(const float4*)&b[l * 8], b1 = *(const float4*)&b[l * 8 + 4];
    float o[8];
    o[0] = (v0.x - mu) * rs * w0.x + b0.x;
    o[1] = (v0.y - mu) * rs * w0.y + b0.y;
    o[2] = (v0.z - mu) * rs * w0.z + b0.z;
    o[3] = (v0.w - mu) * rs * w0.w + b0.w;
    o[4] = (v1.x - mu) * rs * w1.x + b1.x;
    o[5] = (v1.y - mu) * rs * w1.y + b1.y;
    o[6] = (v1.z - mu) * rs * w1.z + b1.z;
    o[7] = (v1.w - mu) * rs * w1.w + b1.w;
    float* po = out + (size_t)row * EE + l * 8;
    *(float4*)po       = make_float4(o[0], o[1], o[2], o[3]);
    *(float4*)(po + 4) = make_float4(o[4], o[5], o[6], o[7]);
    if (out_bf) {
        uint4 pk;
        pk.x = (uint32_t)f2bf(o[0]) | ((uint32_t)f2bf(o[1]) << 16);
        pk.y = (uint32_t)f2bf(o[2]) | ((uint32_t)f2bf(o[3]) << 16);
        pk.z = (uint32_t)f2bf(o[4]) | ((uint32_t)f2bf(o[5]) << 16);
        pk.w = (uint32_t)f2bf(o[6]) | ((uint32_t)f2bf(o[7]) << 16);
        *(uint4*)(out_bf + (size_t)row * EE + l * 8) = pk;
    }
}

// ---------------------------------------------------------------------------
extern "C" void kernel_launch(void* const* d_in, const int* in_sizes, int n_in,
                              void* d_out, int out_size, void* d_ws, size_t ws_size,
                              hipStream_t stream)
{
    const float* src        = (const float*)d_in[0];
    const float* conv_w     = (const float*)d_in[1];
    const float* conv_b     = (const float*)d_in[2];
    const float* in_proj_w  = (const float*)d_in[3];
    const float* in_proj_b  = (const float*)d_in[4];
    const float* out_proj_w = (const float*)d_in[5];
    const float* out_proj_b = (const float*)d_in[6];
    const float* ln1_w      = (const float*)d_in[7];
    const float* ln1_b      = (const float*)d_in[8];
    const float* ln2_w      = (const float*)d_in[9];
    const float* ln2_b      = (const float*)d_in[10];
    const float* w1         = (const float*)d_in[11];
    const float* b1         = (const float*)d_in[12];
    const float* w2         = (const float*)d_in[13];
    const float* b2         = (const float*)d_in[14];

    char*  wsb    = (char*)d_ws;
    float* out    = (float*)d_out;
    u16*   src_bf = (u16*)(wsb + B_SRCBF);
    u16*   lvl_bf = (u16*)(wsb + B_LVLBF);
    u16*   QKV    = (u16*)(wsb + B_QKV);
    u16*   KVs    = (u16*)(wsb + B_KVS);
    u16*   O_bf   = (u16*)(wsb + B_OBF);
    float* X      = (float*)(wsb + B_X);
    u16*   X_bf   = (u16*)(wsb + B_XBF);
    u16*   inw_bf = (u16*)(wsb + B_WBF);
    u16*   outw_bf= inw_bf + 786432;
    u16*   w1_bf  = outw_bf + 262144;
    u16*   w2_bf  = w1_bf + 1048576;
    u16*   cw_bf  = w2_bf + 1048576;
    u16*   FFH    = (u16*)(wsb + B_FFH);

    // 0) cast src + weights to bf16 (+ conv_w repack)
    cast_all_kernel<<<11344, 256, 0, stream>>>(src, in_proj_w, out_proj_w, w1, w2, conv_w,
                                               src_bf, inw_bf, outw_bf, w1_bf, w2_bf, cw_bf);

    // 1) conv pyramid: levels 1..8 in one launch, 9..10 in a tiny tail
    conv_chain_kernel<<<NB * NHEADS * 4, 256, 0, stream>>>(src_bf, lvl_bf, cw_bf, conv_b);
    conv_tail_kernel<<<NB * NHEADS, 256, 0, stream>>>(lvl_bf, cw_bf, conv_b);

    // 2) QKV = src_bf @ in_proj_w^T + b  (16384 x 1536): v6, gx=6, grid 384
    mfma_gemm_big<<<64 * 6, 512, 0, stream>>>(
        src_bf, inw_bf, in_proj_b, QKV, BROWS, EE, 1536, 0, 6);

    // 3) KVs = lvl_bf @ Wkv^T + b_kv  (16368 x 1024): v6, gx=4, grid 256
    mfma_gemm_big<<<64 * 4, 512, 0, stream>>>(
        lvl_bf, inw_bf + (size_t)512 * 512, in_proj_b + 512, KVs, 16368, EE, 1024, 0, 4);

    // 4) attention -> O_bf
    attn_kernel<<<BROWS / 4, 256, 0, stream>>>(QKV, KVs, O_bf);

    // 5) X = O_bf @ out_proj^T + b  (fp32): v4, grid 256
    mfma_gemm<<<64 * 4, 512, 0, stream>>>(
        O_bf, outw_bf, out_proj_b, nullptr, X, nullptr, BROWS, EE, EE, 0, 4);

    // 6) LN1 in place (+ bf16 copy)
    ln_kernel<<<BROWS / 4, 256, 0, stream>>>(X, X, ln1_w, ln1_b, X_bf);

    // 7) FFH = relu(X_bf @ w1^T + b1)  (bf16): v6, gx=8, grid 512
    mfma_gemm_big<<<64 * 8, 512, 0, stream>>>(
        X_bf, w1_bf, b1, FFH, BROWS, EE, DFF, 1, 8);

    // 8) out = FFH @ w2^T + b2 + X_bf  (fp32 out, bf16 residual): v4, grid 256
    mfma_gemm<<<64 * 4, 512, 0, stream>>>(
        FFH, w2_bf, b2, X_bf, out, nullptr, BROWS, DFF, EE, 0, 4);

    // 9) LN2 in place on out
    ln_kernel<<<BROWS / 4, 256, 0, stream>>>(out, out, ln2_w, ln2_b, nullptr);
}

// Round 13
// 234.687 us; speedup vs baseline: 1.0808x; 1.0745x over previous
//
#include <hip/hip_runtime.h>
#include <hip/hip_bf16.h>
#include <stdint.h>
#include <math.h>

// Problem constants
#define NB      16
#define LL      1024
#define EE      512
#define NHEADS  8
#define DFF     2048
#define NLEVELS 10
#define NSCALES 11
#define BROWS   (NB * LL)       // 16384

typedef unsigned short u16;
typedef __attribute__((ext_vector_type(8))) short bf16x8;   // 8 bf16 = 4 VGPRs (MFMA A/B frag)
typedef __attribute__((ext_vector_type(4))) float f32x4;    // MFMA C/D frag

// ---------------- workspace layout (byte offsets) ----------------
static const size_t B_SRCBF = 0;                         // 16,777,216
static const size_t B_LVLBF = 16777216;                  // 16,760,832
static const size_t B_QKV   = 33538048;                  // 50,331,648
static const size_t B_KVS   = 83869696;                  // 33,521,664
static const size_t B_OBF   = 117391360;                 // 16,777,216
static const size_t B_XPRE  = 134168576;                 // 16,777,216 (pre-LN1 bf16)
static const size_t B_OUTBF = 150945792;                 // 16,777,216 (pre-LN2 bf16)
static const size_t B_XBF   = 167723008;                 // 16,777,216 (LN1 out bf16)
static const size_t B_WBF   = 184500224;                 // weights
static const size_t B_FFH   = 0;                         // overlaps dead-by-then buffers

// ---------------- helpers ----------------
__device__ __forceinline__ u16 f2bf(float x) {
    union { float f; uint32_t u; } c; c.f = x;
    uint32_t u = c.u + 0x7FFFu + ((c.u >> 16) & 1u);
    return (u16)(u >> 16);
}
__device__ __forceinline__ float bf2f(u16 v) {
    union { uint32_t u; float f; } c; c.u = ((uint32_t)v) << 16; return c.f;
}
__device__ __forceinline__ uint32_t addbf2(uint32_t a, uint32_t b) {
    float lo = bf2f((u16)(a & 0xFFFF)) + bf2f((u16)(b & 0xFFFF));
    float hi = bf2f((u16)(a >> 16))    + bf2f((u16)(b >> 16));
    return (uint32_t)f2bf(lo) | ((uint32_t)f2bf(hi) << 16);
}
__device__ __forceinline__ void ld8bf(const u16* p, float* f) {
    uint4 r = *(const uint4*)p;
    uint32_t ws[4] = { r.x, r.y, r.z, r.w };
    #pragma unroll
    for (int j = 0; j < 4; j++) {
        union { uint32_t u; float g; } lo, hi;
        lo.u = ws[j] << 16; hi.u = ws[j] & 0xFFFF0000u;
        f[2 * j] = lo.g; f[2 * j + 1] = hi.g;
    }
}
__device__ __forceinline__ void gload16(const u16* g, u16* l) {
    __builtin_amdgcn_global_load_lds(
        (const __attribute__((address_space(1))) void*)g,
        (__attribute__((address_space(3))) void*)l, 16, 0, 0);
}

// ---------------------------------------------------------------------------
// Fused cast kernel: src + 4 weight tensors -> bf16, plus conv_w repack.
// ---------------------------------------------------------------------------
__global__ void cast_all_kernel(const float* __restrict__ s0, const float* __restrict__ s1,
                                const float* __restrict__ s2, const float* __restrict__ s3,
                                const float* __restrict__ s4, const float* __restrict__ cw,
                                u16* __restrict__ d0, u16* __restrict__ d1,
                                u16* __restrict__ d2, u16* __restrict__ d3,
                                u16* __restrict__ d4, u16* __restrict__ dw)
{
    int bid = blockIdx.x;
    if (bid >= 11264) {   // conv_w repack: 81920 outputs
        int base = (bid - 11264) * 1024 + threadIdx.x * 4;
        #pragma unroll
        for (int j = 0; j < 4; j++) {
            int idx = base + j;
            int lvl = idx >> 13, rem = idx & 8191;
            int o = rem >> 7, ck = rem & 127;
            int k = ck >> 6, ci = ck & 63;
            dw[idx] = f2bf(cw[(lvl << 13) + (o << 7) + (ci << 1) + k]);
        }
        return;
    }
    const float* s; u16* d; int nt;
    if      (bid < 8192)  { s = s0; d = d0; nt = 2097152; }
    else if (bid < 8960)  { bid -= 8192;  s = s1; d = d1; nt = 196608; }
    else if (bid < 9216)  { bid -= 8960;  s = s2; d = d2; nt = 65536;  }
    else if (bid < 10240) { bid -= 9216;  s = s3; d = d3; nt = 262144; }
    else                  { bid -= 10240; s = s4; d = d4; nt = 262144; }
    int i = bid * 256 + threadIdx.x;
    if (i < nt) {
        float4 v = ((const float4*)s)[i];
        uint2 o;
        o.x = (uint32_t)f2bf(v.x) | ((uint32_t)f2bf(v.y) << 16);
        o.y = (uint32_t)f2bf(v.z) | ((uint32_t)f2bf(v.w) << 16);
        ((uint2*)d)[i] = o;
    }
}

// ---------------------------------------------------------------------------
// Conv chain kernel: levels 1..8 in ONE launch (unchanged).
// ---------------------------------------------------------------------------
__global__ __launch_bounds__(256, 2)
void conv_chain_kernel(const u16* __restrict__ src_bf, u16* __restrict__ lvl_bf,
                       const u16* __restrict__ cw, const float* __restrict__ cb)
{
    __shared__ u16 BIG[16384];   // 32KB
    __shared__ u16 MID[8192];    // 16KB
    __shared__ u16 WB[8192];     // 16KB: per-level weights [o][128]
    const int tid = threadIdx.x;
    const int l = tid & 63, w = tid >> 6;
    const int bid = blockIdx.x;          // n*32 + h*4 + q
    const int q  = bid & 3;
    const int h  = (bid >> 2) & 7;
    const int n  = bid >> 5;

    {
        const u16* base = src_bf + ((size_t)n * 1024 + q * 256) * 512 + h * 64;
        #pragma unroll
        for (int j = 0; j < 8; j++) {
            int c = j * 256 + w * 64 + l;
            int row = c >> 3, lch = c & 7;
            int gch = lch ^ (row & 7);
            gload16(base + (size_t)row * 512 + gch * 8,
                    BIG + (size_t)(j * 256 + w * 64) * 8);
        }
    }

    const u16* IN = BIG;
    u16* OUTb = MID;
    int R = 128;
    int T = 512;
    size_t rowOff = 0;
    for (int lvl = 1; lvl <= 8; lvl++) {
        {
            const u16* wsrc = cw + (size_t)(lvl - 1) * 8192;
            #pragma unroll
            for (int j = 0; j < 4; j++) {
                int c = j * 256 + w * 64 + l;
                int o = c >> 4, lch = c & 15;
                int gch = lch ^ (o & 7);
                gload16(wsrc + o * 128 + gch * 8, WB + (size_t)(j * 256 + w * 64) * 8);
            }
        }
        asm volatile("s_waitcnt vmcnt(0)" ::: "memory");
        __syncthreads();

        const int nrt = (R + 15) >> 4;
        const int maxil = 2 * R - 1;
        for (int f = w; f < nrt * 4; f += 4) {
            int rt = f >> 2, nc = f & 3;
            int o = nc * 16 + (l & 15);
            f32x4 acc = {0.f, 0.f, 0.f, 0.f};
            #pragma unroll
            for (int s = 0; s < 4; s++) {
                int il = 2 * (rt * 16 + (l & 15)) + (s >> 1);
                if (il > maxil) il = maxil;
                int ach = (((s & 1) * 4) + (l >> 4)) ^ (il & 7);
                bf16x8 av = *(const bf16x8*)(IN + il * 64 + ach * 8);
                int bch = (s * 4 + (l >> 4)) ^ (o & 7);
                bf16x8 bv = *(const bf16x8*)(WB + o * 128 + bch * 8);
                acc = __builtin_amdgcn_mfma_f32_16x16x32_bf16(av, bv, acc, 0, 0, 0);
            }
            float bb = cb[(lvl - 1) * 64 + o];
            #pragma unroll
            for (int reg = 0; reg < 4; reg++) {
                int rloc = rt * 16 + (l >> 4) * 4 + reg;
                if (rloc < R) {
                    float v = fmaxf(acc[reg] + bb, 0.f);
                    u16 b16 = f2bf(v);
                    lvl_bf[(rowOff + (size_t)n * T + (size_t)q * R + rloc) * 512 + h * 64 + o] = b16;
                    OUTb[rloc * 64 + (((o >> 3) ^ (rloc & 7)) << 3) + (o & 7)] = b16;
                }
            }
        }
        __syncthreads();
        const u16* tmp = IN; IN = OUTb; OUTb = (u16*)tmp;
        rowOff += (size_t)16 * T;
        T >>= 1; R >>= 1;
    }
}

// ---------------------------------------------------------------------------
// Conv tail: levels 9 and 10 (tiny). Block per (n,h).
// ---------------------------------------------------------------------------
__global__ void conv_tail_kernel(u16* __restrict__ lvl_bf, const u16* __restrict__ cw,
                                 const float* __restrict__ cb)
{
    const int h = blockIdx.x & 7, n = blockIdx.x >> 3;
    const int tid = threadIdx.x;
    __shared__ float L8s[4][64];
    __shared__ float L9s[2][64];
    {
        int r = tid >> 6, c = tid & 63;
        L8s[r][c] = bf2f(lvl_bf[((size_t)16256 + n * 4 + r) * 512 + h * 64 + c]);
    }
    __syncthreads();
    if (tid < 128) {
        int t = tid >> 6, o = tid & 63;
        const u16* wr = cw + (size_t)8 * 8192 + o * 128;
        float acc = cb[8 * 64 + o];
        #pragma unroll
        for (int k = 0; k < 2; k++)
            #pragma unroll 16
            for (int ci = 0; ci < 64; ci++)
                acc += L8s[2 * t + k][ci] * bf2f(wr[k * 64 + ci]);
        acc = fmaxf(acc, 0.f);
        L9s[t][o] = acc;
        lvl_bf[((size_t)16320 + n * 2 + t) * 512 + h * 64 + o] = f2bf(acc);
    }
    __syncthreads();
    if (tid < 64) {
        int o = tid;
        const u16* wr = cw + (size_t)9 * 8192 + o * 128;
        float acc = cb[9 * 64 + o];
        #pragma unroll
        for (int k = 0; k < 2; k++)
            #pragma unroll 16
            for (int ci = 0; ci < 64; ci++)
                acc += L9s[k][ci] * bf2f(wr[k * 64 + ci]);
        acc = fmaxf(acc, 0.f);
        lvl_bf[((size_t)16352 + n) * 512 + h * 64 + o] = f2bf(acc);
    }
}

// ---------------------------------------------------------------------------
// bf16 MFMA GEMM v4 (round-10 proven): 256x128, BK=32, 8 waves (4M x 2N),
// 3-ring 72KB, single barrier/iter, involution swizzle p=c^((row>>1)&3),
// setprio around MFMA. Output ALWAYS bf16 (Cb); optional bf16 residual
// (added in the coalesced store phase via unpack-add-repack).
// ---------------------------------------------------------------------------
__global__ __launch_bounds__(512, 4)
void mfma_gemm(const u16* __restrict__ A, const u16* __restrict__ W,
               const float* __restrict__ bias,
               const u16* __restrict__ resb,
               u16* __restrict__ Cb,
               int M, int K, int N, int relu, int gx)
{
    __shared__ u16 lds[36864];   // 72 KB: 3 buffers x (A 16KB + B 8KB)
    const int tid = threadIdx.x;
    const int l = tid & 63, w = tid >> 6;     // 8 waves
    const int wm = w >> 1, wn = w & 1;        // 4M x 2N wave grid

    const int nwg = gridDim.x;
    const int q = nwg >> 3, r = nwg & 7;
    const int xcd = blockIdx.x & 7, idx = blockIdx.x >> 3;
    const int lin = (xcd < r ? xcd * (q + 1) : r * (q + 1) + (xcd - r) * q) + idx;
    const int by = lin / gx, bx = lin - by * gx;
    const int rowBase = by * 256, colBase = bx * 128;

    f32x4 acc[4][4];
    #pragma unroll
    for (int m = 0; m < 4; m++)
        #pragma unroll
        for (int n = 0; n < 4; n++) acc[m][n] = 0.f;

    const u16* gApt[2];
    const u16* gBpt;
    #pragma unroll
    for (int i = 0; i < 2; i++) {
        int G = i * 512 + tid;
        int row = G >> 2, p = G & 3;
        int c = p ^ ((row >> 1) & 3);
        int grow = rowBase + row; if (grow > M - 1) grow = M - 1;
        gApt[i] = A + (size_t)grow * K + c * 8;
    }
    {
        int G = tid;
        int row = G >> 2, p = G & 3;
        int c = p ^ ((row >> 1) & 3);
        gBpt = W + (size_t)(colBase + row) * K + c * 8;
    }

    const int NT = K >> 5;
    auto STAGE = [&](int tt, int buf) {
        const int kb = tt << 5;
        u16* dA = lds + buf * 12288;
        u16* dB = dA + 8192;
        gload16(gApt[0] + kb, dA + (size_t)(w * 64) * 8);
        gload16(gApt[1] + kb, dA + (size_t)(512 + w * 64) * 8);
        gload16(gBpt + kb, dB + (size_t)(w * 64) * 8);
    };
    STAGE(0, 0);
    if (NT > 1) STAGE(1, 1);

    int cbuf = 0, sbuf = 2;
    for (int t = 0; t < NT; ++t) {
        if (t + 1 < NT) asm volatile("s_waitcnt vmcnt(3)" ::: "memory");
        else            asm volatile("s_waitcnt vmcnt(0)" ::: "memory");
        __builtin_amdgcn_s_barrier();
        __builtin_amdgcn_sched_barrier(0);
        if (t + 2 < NT) STAGE(t + 2, sbuf);

        const u16* Ab = lds + cbuf * 12288;
        const u16* Bb = Ab + 8192;
        const int c = l >> 4;
        bf16x8 av[4], bv[4];
        #pragma unroll
        for (int fr = 0; fr < 4; fr++) {
            int row = wm * 64 + fr * 16 + (l & 15);
            av[fr] = *(const bf16x8*)(Ab + row * 32 + ((c ^ ((row >> 1) & 3)) * 8));
        }
        #pragma unroll
        for (int fc = 0; fc < 4; fc++) {
            int col = wn * 64 + fc * 16 + (l & 15);
            bv[fc] = *(const bf16x8*)(Bb + col * 32 + ((c ^ ((col >> 1) & 3)) * 8));
        }
        __builtin_amdgcn_s_setprio(1);
        #pragma unroll
        for (int m = 0; m < 4; m++)
            #pragma unroll
            for (int n = 0; n < 4; n++)
                acc[m][n] = __builtin_amdgcn_mfma_f32_16x16x32_bf16(av[m], bv[n], acc[m][n], 0, 0, 0);
        __builtin_amdgcn_s_setprio(0);

        cbuf = (cbuf == 2) ? 0 : cbuf + 1;
        sbuf = (sbuf == 2) ? 0 : sbuf + 1;
    }
    __builtin_amdgcn_s_barrier();           // protect epilogue LDS scratch
    __builtin_amdgcn_sched_barrier(0);

    // ---- epilogue: per-wave LDS transpose -> coalesced bf16 stores ----
    const int cc = colBase + wn * 64 + (l & 15);
    float bs4[4];
    #pragma unroll
    for (int n = 0; n < 4; n++) bs4[n] = bias[cc + n * 16];

    u16* WS = lds + w * 2048;   // 4 KB/wave (32 rows x 64 u16)
    #pragma unroll
    for (int hh = 0; hh < 2; hh++) {
        #pragma unroll
        for (int mi = 0; mi < 2; mi++) {
            #pragma unroll
            for (int n = 0; n < 4; n++) {
                int colv = n * 16 + (l & 15);
                #pragma unroll
                for (int reg = 0; reg < 4; reg++) {
                    int rowh = mi * 16 + (l >> 4) * 4 + reg;
                    float v = acc[hh * 2 + mi][n][reg] + bs4[n];
                    if (relu) v = fmaxf(v, 0.f);
                    WS[rowh * 64 + (colv ^ (((rowh >> 2) & 3) << 4))] = f2bf(v);
                }
            }
        }
        asm volatile("s_waitcnt lgkmcnt(0)" ::: "memory");
        __builtin_amdgcn_sched_barrier(0);
        #pragma unroll
        for (int j = 0; j < 4; j++) {
            int rowh = (l >> 3) + 8 * j;
            int col8 = (l & 7) * 8;
            int colx = col8 ^ (((rowh >> 2) & 3) << 4);
            uint4 v = *(const uint4*)(WS + rowh * 64 + colx);
            int grow = rowBase + wm * 64 + hh * 32 + rowh;
            if (grow < M) {
                int gcol = colBase + wn * 64 + col8;
                if (resb) {
                    uint4 rb = *(const uint4*)&resb[(size_t)grow * N + gcol];
                    v.x = addbf2(v.x, rb.x);
                    v.y = addbf2(v.y, rb.y);
                    v.z = addbf2(v.z, rb.z);
                    v.w = addbf2(v.w, rb.w);
                }
                *(uint4*)(Cb + (size_t)grow * N + gcol) = v;
            }
        }
        asm volatile("s_waitcnt lgkmcnt(0)" ::: "memory");
    }
}

// ---------------------------------------------------------------------------
// Attention (bf16 in/out), unchanged.
// ---------------------------------------------------------------------------
__global__ void attn_kernel(const u16* __restrict__ QKV, const u16* __restrict__ KVs,
                            u16* __restrict__ O)
{
    const int wv   = threadIdx.x >> 6;
    const int lane = threadIdx.x & 63;
    const int b    = blockIdx.x * 4 + wv;
    const int h    = lane >> 3;
    const int d8   = lane & 7;
    const int n = b >> 10, pos = b & 1023;

    float q[8];
    ld8bf(QKV + (size_t)b * 1536 + h * 64 + d8 * 8, q);

    float sc[NSCALES];
    {
        float kk[8];
        ld8bf(QKV + (size_t)b * 1536 + 512 + h * 64 + d8 * 8, kk);
        float p = 0.f;
        #pragma unroll
        for (int j = 0; j < 8; j++) p += q[j] * kk[j];
        p += __shfl_xor(p, 1); p += __shfl_xor(p, 2); p += __shfl_xor(p, 4);
        sc[0] = p * 0.125f;
    }
    {
        int rowOff = 0;
        #pragma unroll
        for (int s = 1; s <= NLEVELS; s++) {
            int Ls = 1024 >> s;
            int row = rowOff + n * Ls + (pos >> s);
            float kk[8];
            ld8bf(KVs + (size_t)row * 1024 + h * 64 + d8 * 8, kk);
            float p = 0.f;
            #pragma unroll
            for (int j = 0; j < 8; j++) p += q[j] * kk[j];
            p += __shfl_xor(p, 1); p += __shfl_xor(p, 2); p += __shfl_xor(p, 4);
            sc[s] = p * 0.125f;
            rowOff += 16 * Ls;
        }
    }
    float m = sc[0];
    #pragma unroll
    for (int s = 1; s < NSCALES; s++) m = fmaxf(m, sc[s]);
    float sum = 0.f;
    #pragma unroll
    for (int s = 0; s < NSCALES; s++) { sc[s] = __expf(sc[s] - m); sum += sc[s]; }
    float inv = 1.f / sum;

    float o[8] = {};
    {
        float vv[8];
        ld8bf(QKV + (size_t)b * 1536 + 1024 + h * 64 + d8 * 8, vv);
        float a = sc[0] * inv;
        #pragma unroll
        for (int j = 0; j < 8; j++) o[j] += a * vv[j];
    }
    {
        int rowOff = 0;
        #pragma unroll
        for (int s = 1; s <= NLEVELS; s++) {
            int Ls = 1024 >> s;
            int row = rowOff + n * Ls + (pos >> s);
            float vv[8];
            ld8bf(KVs + (size_t)row * 1024 + 512 + h * 64 + d8 * 8, vv);
            float a = sc[s] * inv;
            #pragma unroll
            for (int j = 0; j < 8; j++) o[j] += a * vv[j];
            rowOff += 16 * Ls;
        }
    }
    uint4 pk;
    pk.x = (uint32_t)f2bf(o[0]) | ((uint32_t)f2bf(o[1]) << 16);
    pk.y = (uint32_t)f2bf(o[2]) | ((uint32_t)f2bf(o[3]) << 16);
    pk.z = (uint32_t)f2bf(o[4]) | ((uint32_t)f2bf(o[5]) << 16);
    pk.w = (uint32_t)f2bf(o[6]) | ((uint32_t)f2bf(o[7]) << 16);
    *(uint4*)(O + (size_t)b * 512 + h * 64 + d8 * 8) = pk;
}

// ---------------------------------------------------------------------------
// LayerNorm over E=512, bf16 input: one wave per row (4 rows/block).
// Optional bf16 output and/or fp32 output.
// ---------------------------------------------------------------------------
__global__ void ln_bf_kernel(const u16* __restrict__ in_bf,
                             const float* __restrict__ w, const float* __restrict__ b,
                             u16* __restrict__ out_bf, float* __restrict__ out_f)
{
    const int l = threadIdx.x & 63;
    const int row = blockIdx.x * 4 + (threadIdx.x >> 6);
    float v[8];
    ld8bf(in_bf + (size_t)row * EE + l * 8, v);
    float s = 0.f, s2 = 0.f;
    #pragma unroll
    for (int j = 0; j < 8; j++) { s += v[j]; s2 += v[j] * v[j]; }
    #pragma unroll
    for (int m = 1; m < 64; m <<= 1) { s += __shfl_xor(s, m); s2 += __shfl_xor(s2, m); }
    float mu  = s * (1.f / 512.f);
    float var = s2 * (1.f / 512.f) - mu * mu;
    float rs  = rsqrtf(var + 1e-5f);
    float4 w0 = *(const float4*)&w[l * 8], w1 = *(const float4*)&w[l * 8 + 4];
    float4 b0 = *(const float4*)&b[l * 8], b1 = *(const float4*)&b[l * 8 + 4];
    float o[8];
    o[0] = (v[0] - mu) * rs * w0.x + b0.x;
    o[1] = (v[1] - mu) * rs * w0.y + b0.y;
    o[2] = (v[2] - mu) * rs * w0.z + b0.z;
    o[3] = (v[3] - mu) * rs * w0.w + b0.w;
    o[4] = (v[4] - mu) * rs * w1.x + b1.x;
    o[5] = (v[5] - mu) * rs * w1.y + b1.y;
    o[6] = (v[6] - mu) * rs * w1.z + b1.z;
    o[7] = (v[7] - mu) * rs * w1.w + b1.w;
    if (out_bf) {
        uint4 pk;
        pk.x = (uint32_t)f2bf(o[0]) | ((uint32_t)f2bf(o[1]) << 16);
        pk.y = (uint32_t)f2bf(o[2]) | ((uint32_t)f2bf(o[3]) << 16);
        pk.z = (uint32_t)f2bf(o[4]) | ((uint32_t)f2bf(o[5]) << 16);
        pk.w = (uint32_t)f2bf(o[6]) | ((uint32_t)f2bf(o[7]) << 16);
        *(uint4*)(out_bf + (size_t)row * EE + l * 8) = pk;
    }
    if (out_f) {
        float* po = out_f + (size_t)row * EE + l * 8;
        *(float4*)po       = make_float4(o[0], o[1], o[2], o[3]);
        *(float4*)(po + 4) = make_float4(o[4], o[5], o[6], o[7]);
    }
}

// ---------------------------------------------------------------------------
extern "C" void kernel_launch(void* const* d_in, const int* in_sizes, int n_in,
                              void* d_out, int out_size, void* d_ws, size_t ws_size,
                              hipStream_t stream)
{
    const float* src        = (const float*)d_in[0];
    const float* conv_w     = (const float*)d_in[1];
    const float* conv_b     = (const float*)d_in[2];
    const float* in_proj_w  = (const float*)d_in[3];
    const float* in_proj_b  = (const float*)d_in[4];
    const float* out_proj_w = (const float*)d_in[5];
    const float* out_proj_b = (const float*)d_in[6];
    const float* ln1_w      = (const float*)d_in[7];
    const float* ln1_b      = (const float*)d_in[8];
    const float* ln2_w      = (const float*)d_in[9];
    const float* ln2_b      = (const float*)d_in[10];
    const float* w1         = (const float*)d_in[11];
    const float* b1         = (const float*)d_in[12];
    const float* w2         = (const float*)d_in[13];
    const float* b2         = (const float*)d_in[14];

    char*  wsb    = (char*)d_ws;
    float* out    = (float*)d_out;
    u16*   src_bf = (u16*)(wsb + B_SRCBF);
    u16*   lvl_bf = (u16*)(wsb + B_LVLBF);
    u16*   QKV    = (u16*)(wsb + B_QKV);
    u16*   KVs    = (u16*)(wsb + B_KVS);
    u16*   O_bf   = (u16*)(wsb + B_OBF);
    u16*   XPRE   = (u16*)(wsb + B_XPRE);   // pre-LN1 (out_proj output)
    u16*   OUTBF  = (u16*)(wsb + B_OUTBF);  // pre-LN2 (FFN2 output)
    u16*   X_bf   = (u16*)(wsb + B_XBF);    // LN1 output
    u16*   inw_bf = (u16*)(wsb + B_WBF);
    u16*   outw_bf= inw_bf + 786432;
    u16*   w1_bf  = outw_bf + 262144;
    u16*   w2_bf  = w1_bf + 1048576;
    u16*   cw_bf  = w2_bf + 1048576;
    u16*   FFH    = (u16*)(wsb + B_FFH);

    // 0) cast src + weights to bf16 (+ conv_w repack)
    cast_all_kernel<<<11344, 256, 0, stream>>>(src, in_proj_w, out_proj_w, w1, w2, conv_w,
                                               src_bf, inw_bf, outw_bf, w1_bf, w2_bf, cw_bf);

    // 1) conv pyramid: levels 1..8 in one launch, 9..10 in a tiny tail
    conv_chain_kernel<<<NB * NHEADS * 4, 256, 0, stream>>>(src_bf, lvl_bf, cw_bf, conv_b);
    conv_tail_kernel<<<NB * NHEADS, 256, 0, stream>>>(lvl_bf, cw_bf, conv_b);

    // 2) QKV = src_bf @ in_proj_w^T + b  (16384 x 1536), grid 64 x 12
    mfma_gemm<<<64 * 12, 512, 0, stream>>>(
        src_bf, inw_bf, in_proj_b, nullptr, QKV, BROWS, EE, 1536, 0, 12);

    // 3) KVs = lvl_bf @ Wkv^T + b_kv  (16368 x 1024), grid 64 x 8
    mfma_gemm<<<64 * 8, 512, 0, stream>>>(
        lvl_bf, inw_bf + (size_t)512 * 512, in_proj_b + 512, nullptr, KVs,
        16368, EE, 1024, 0, 8);

    // 4) attention -> O_bf
    attn_kernel<<<BROWS / 4, 256, 0, stream>>>(QKV, KVs, O_bf);

    // 5) XPRE = O_bf @ out_proj^T + b  (bf16), grid 64 x 4
    mfma_gemm<<<64 * 4, 512, 0, stream>>>(
        O_bf, outw_bf, out_proj_b, nullptr, XPRE, BROWS, EE, EE, 0, 4);

    // 6) LN1: X_bf = LN(XPRE)  (bf16 -> bf16)
    ln_bf_kernel<<<BROWS / 4, 256, 0, stream>>>(XPRE, ln1_w, ln1_b, X_bf, nullptr);

    // 7) FFH = relu(X_bf @ w1^T + b1)  (bf16), grid 64 x 16
    mfma_gemm<<<64 * 16, 512, 0, stream>>>(
        X_bf, w1_bf, b1, nullptr, FFH, BROWS, EE, DFF, 1, 16);

    // 8) OUTBF = FFH @ w2^T + b2 + X_bf  (bf16 + bf16 residual), grid 64 x 4
    mfma_gemm<<<64 * 4, 512, 0, stream>>>(
        FFH, w2_bf, b2, X_bf, OUTBF, BROWS, DFF, EE, 0, 4);

    // 9) LN2: out = LN(OUTBF)  (bf16 -> fp32 final)
    ln_bf_kernel<<<BROWS / 4, 256, 0, stream>>>(OUTBF, ln2_w, ln2_b, nullptr, out);
}